// Round 1
// baseline (288.584 us; speedup 1.0000x reference)
//
#include <hip/hip_runtime.h>
#include <math.h>

#define T_SEQ 2048
#define NH    16
#define HD    64
#define DIM   1024
#define WIN   256

// ---------------------------------------------------------------------------
// Kernel 1: sliding-window attention, fp32, thread-per-query.
// grid = (T/64, H), block = 64 threads (1 wave). Each thread owns one query.
// K/V staged in LDS in 64-row chunks; no online-max (scores bounded ~|8|).
// ---------------------------------------------------------------------------
__global__ __launch_bounds__(64) void attn_kernel(const float* __restrict__ qg,
                                                  const float* __restrict__ kg,
                                                  const float* __restrict__ vg,
                                                  float* __restrict__ y) {
    __shared__ float sK[64][64];
    __shared__ float sV[64][64];

    const int tid = threadIdx.x;
    const int q0  = blockIdx.x * 64;
    const int h   = blockIdx.y;
    const int qi  = q0 + tid;
    const size_t headBase = (size_t)h * T_SEQ * HD;

    // load this thread's query row (64 floats) into registers
    float4 qv[16];
    const float4* qrow = (const float4*)(qg + headBase + (size_t)qi * HD);
#pragma unroll
    for (int c = 0; c < 16; ++c) qv[c] = qrow[c];

    float4 acc[16];
#pragma unroll
    for (int c = 0; c < 16; ++c) acc[c] = make_float4(0.f, 0.f, 0.f, 0.f);
    float l = 0.f;

    int lo = q0 - (WIN - 1);
    if (lo < 0) lo = 0;
    const int kc0 = lo & ~63;

    for (int kc = kc0; kc <= q0 + 63; kc += 64) {
        __syncthreads();
        // cooperative stage of K,V chunk rows [kc, kc+64)
        const float4* kchunk = (const float4*)(kg + headBase + (size_t)kc * HD);
        const float4* vchunk = (const float4*)(vg + headBase + (size_t)kc * HD);
        float4* sk4 = (float4*)&sK[0][0];
        float4* sv4 = (float4*)&sV[0][0];
#pragma unroll
        for (int i = 0; i < 16; ++i) {
            sk4[tid + i * 64] = kchunk[tid + i * 64];
            sv4[tid + i * 64] = vchunk[tid + i * 64];
        }
        __syncthreads();

        for (int j = 0; j < 64; ++j) {
            const int jg = kc + j;
            const bool valid = (jg <= qi) && (jg > qi - WIN);
            if (__ballot(valid) == 0ULL) continue;

            const float4* krow = (const float4*)&sK[j][0];
            float4 d4 = make_float4(0.f, 0.f, 0.f, 0.f);
#pragma unroll
            for (int c = 0; c < 16; ++c) {
                float4 kv = krow[c];
                d4.x = fmaf(qv[c].x, kv.x, d4.x);
                d4.y = fmaf(qv[c].y, kv.y, d4.y);
                d4.z = fmaf(qv[c].z, kv.z, d4.z);
                d4.w = fmaf(qv[c].w, kv.w, d4.w);
            }
            const float dot = (d4.x + d4.y) + (d4.z + d4.w);
            const float s = dot * 0.125f;  // 1/sqrt(64)
            const float p = valid ? __expf(s) : 0.f;
            l += p;

            const float4* vrow = (const float4*)&sV[j][0];
#pragma unroll
            for (int c = 0; c < 16; ++c) {
                float4 vv = vrow[c];
                acc[c].x = fmaf(p, vv.x, acc[c].x);
                acc[c].y = fmaf(p, vv.y, acc[c].y);
                acc[c].z = fmaf(p, vv.z, acc[c].z);
                acc[c].w = fmaf(p, vv.w, acc[c].w);
            }
        }
    }

    const float rl = 1.f / l;  // l >= exp(s_self) > 0 always (self-attention)
    float4* yo = (float4*)(y + (size_t)qi * DIM + h * HD);
#pragma unroll
    for (int c = 0; c < 16; ++c) {
        float4 a = acc[c];
        yo[c] = make_float4(a.x * rl, a.y * rl, a.z * rl, a.w * rl);
    }
}

// ---------------------------------------------------------------------------
// Kernel 2: out = y @ W, 2048x1024 @ 1024x1024, fp32 LDS-tiled.
// 64x64 tile, BK=16, 256 threads, 4x4 micro-tile per thread.
// A-tile stored transposed As[k][m] (padded) so fragment reads are b128.
// ---------------------------------------------------------------------------
__global__ __launch_bounds__(256) void proj_kernel(const float* __restrict__ A,
                                                   const float* __restrict__ W,
                                                   float* __restrict__ out) {
    __shared__ float As[16][68];  // [k][m], padded to 68 (16B-aligned rows)
    __shared__ float Bs[16][64];  // [k][n]

    const int t  = threadIdx.x;
    const int tx = t & 15;
    const int ty = t >> 4;
    const int m0 = blockIdx.y * 64;
    const int n0 = blockIdx.x * 64;

    float acc[4][4];
#pragma unroll
    for (int i = 0; i < 4; ++i)
#pragma unroll
        for (int j = 0; j < 4; ++j) acc[i][j] = 0.f;

    for (int k0 = 0; k0 < DIM; k0 += 16) {
        // A tile 64x16 -> transposed into As[k][m]
        {
            const int m  = t >> 2;
            const int kk = (t & 3) * 4;
            float4 a = *(const float4*)(A + (size_t)(m0 + m) * DIM + k0 + kk);
            As[kk + 0][m] = a.x;
            As[kk + 1][m] = a.y;
            As[kk + 2][m] = a.z;
            As[kk + 3][m] = a.w;
        }
        // B tile 16x64 straight
        {
            const int kk = t >> 4;
            const int n  = (t & 15) * 4;
            *(float4*)&Bs[kk][n] =
                *(const float4*)(W + (size_t)(k0 + kk) * DIM + n0 + n);
        }
        __syncthreads();

#pragma unroll
        for (int kk = 0; kk < 16; ++kk) {
            float4 av = *(const float4*)&As[kk][ty * 4];
            float4 bv = *(const float4*)&Bs[kk][tx * 4];
            acc[0][0] = fmaf(av.x, bv.x, acc[0][0]);
            acc[0][1] = fmaf(av.x, bv.y, acc[0][1]);
            acc[0][2] = fmaf(av.x, bv.z, acc[0][2]);
            acc[0][3] = fmaf(av.x, bv.w, acc[0][3]);
            acc[1][0] = fmaf(av.y, bv.x, acc[1][0]);
            acc[1][1] = fmaf(av.y, bv.y, acc[1][1]);
            acc[1][2] = fmaf(av.y, bv.z, acc[1][2]);
            acc[1][3] = fmaf(av.y, bv.w, acc[1][3]);
            acc[2][0] = fmaf(av.z, bv.x, acc[2][0]);
            acc[2][1] = fmaf(av.z, bv.y, acc[2][1]);
            acc[2][2] = fmaf(av.z, bv.z, acc[2][2]);
            acc[2][3] = fmaf(av.z, bv.w, acc[2][3]);
            acc[3][0] = fmaf(av.w, bv.x, acc[3][0]);
            acc[3][1] = fmaf(av.w, bv.y, acc[3][1]);
            acc[3][2] = fmaf(av.w, bv.z, acc[3][2]);
            acc[3][3] = fmaf(av.w, bv.w, acc[3][3]);
        }
        __syncthreads();
    }

#pragma unroll
    for (int i = 0; i < 4; ++i) {
        float4 o = make_float4(acc[i][0], acc[i][1], acc[i][2], acc[i][3]);
        *(float4*)(out + (size_t)(m0 + ty * 4 + i) * DIM + n0 + tx * 4) = o;
    }
}

extern "C" void kernel_launch(void* const* d_in, const int* in_sizes, int n_in,
                              void* d_out, int out_size, void* d_ws, size_t ws_size,
                              hipStream_t stream) {
    const float* q = (const float*)d_in[0];
    const float* k = (const float*)d_in[1];
    const float* v = (const float*)d_in[2];
    const float* W = (const float*)d_in[3];
    float* out = (float*)d_out;
    float* y   = (float*)d_ws;  // (T, DIM) fp32 intermediate = 8 MB

    dim3 gA(T_SEQ / 64, NH);
    attn_kernel<<<gA, 64, 0, stream>>>(q, k, v, y);

    dim3 gP(DIM / 64, T_SEQ / 64);
    proj_kernel<<<gP, 256, 0, stream>>>(y, W, out);
}

// Round 2
// 87.388 us; speedup vs baseline: 3.3023x; 3.3023x over previous
//
#include <hip/hip_runtime.h>
#include <math.h>

#define T_SEQ 2048
#define NH    16
#define HD    64
#define DIM   1024
#define WIN   256

typedef __attribute__((ext_vector_type(4))) float f32x4;
typedef __attribute__((ext_vector_type(8))) short s16x8;
typedef unsigned short u16;

static __device__ __forceinline__ u16 f2bf(float f) {
    unsigned u = __builtin_bit_cast(unsigned, f);
    u += 0x7fff + ((u >> 16) & 1);   // RNE; inputs are finite
    return (u16)(u >> 16);
}

static __device__ __forceinline__ int fV(int d) { return (d & 7) ^ ((d >> 3) & 7); }

// ---------------------------------------------------------------------------
// Sliding-window attention, bf16 MFMA flash-style.
// grid=(T/64, H), block=256 (4 waves). Wave w owns queries [q0+16w, q0+16w+16).
// K/V staged per 64-key chunk fp32->bf16 into swizzled LDS (V transposed).
// S = Q K^T via mfma_16x16x32_bf16; P through per-wave LDS to A-layout; O = P V.
// No online max: scores ~N(0,1), exp safe (validated round 1).
// ---------------------------------------------------------------------------
__global__ __launch_bounds__(256) void attn_kernel(const float* __restrict__ qg,
                                                   const float* __restrict__ kg,
                                                   const float* __restrict__ vg,
                                                   float* __restrict__ y) {
    __shared__ __align__(16) char sK[64 * 128];     // bf16 [key][d], swz (key&7)<<4
    __shared__ __align__(16) char sV[64 * 128];     // bf16 [d][key], swz fV(d)<<4
    __shared__ __align__(16) char sP[4][16 * 128];  // per-wave bf16 [q][key], swz (q&7)<<4

    const int t    = threadIdx.x;
    const int lane = t & 63;
    const int w    = t >> 6;
    const int q0   = blockIdx.x * 64;
    const int h    = blockIdx.y;
    const size_t headBase = (size_t)h * T_SEQ * HD;

    const int lr = lane & 15;   // row/col index within fragment
    const int lg = lane >> 4;   // k-group

    // Q A-fragments: lane holds Q[q0+16w+lr][8*lg + e + 32*s]
    s16x8 qf[2];
    {
        const float* qrow = qg + headBase + (size_t)(q0 + w * 16 + lr) * HD + lg * 8;
#pragma unroll
        for (int s = 0; s < 2; ++s) {
            float4 a = *(const float4*)(qrow + 32 * s);
            float4 b = *(const float4*)(qrow + 32 * s + 4);
            s16x8 f;
            f[0] = f2bf(a.x); f[1] = f2bf(a.y); f[2] = f2bf(a.z); f[3] = f2bf(a.w);
            f[4] = f2bf(b.x); f[5] = f2bf(b.y); f[6] = f2bf(b.z); f[7] = f2bf(b.w);
            qf[s] = f;
        }
    }

    f32x4 o[4];
#pragma unroll
    for (int i = 0; i < 4; ++i) o[i] = (f32x4){0.f, 0.f, 0.f, 0.f};
    float lsum[4] = {0.f, 0.f, 0.f, 0.f};

    int lo = q0 - (WIN - 1);
    if (lo < 0) lo = 0;
    const int kc0 = lo & ~63;

    const int srow = t >> 2;         // staging: row 0..63
    const int sd0  = (t & 3) * 16;   // staging: d-base

    for (int kc = kc0; kc <= q0; kc += 64) {
        __syncthreads();  // previous chunk's LDS reads done before overwrite
        // ---- stage K [key][d] and V transposed [d][key], fp32 -> bf16 ----
        {
            const float* ksrc = kg + headBase + (size_t)(kc + srow) * HD + sd0;
            float4 k0 = *(const float4*)(ksrc);
            float4 k1 = *(const float4*)(ksrc + 4);
            float4 k2 = *(const float4*)(ksrc + 8);
            float4 k3 = *(const float4*)(ksrc + 12);
            s16x8 c0, c1;
            c0[0] = f2bf(k0.x); c0[1] = f2bf(k0.y); c0[2] = f2bf(k0.z); c0[3] = f2bf(k0.w);
            c0[4] = f2bf(k1.x); c0[5] = f2bf(k1.y); c0[6] = f2bf(k1.z); c0[7] = f2bf(k1.w);
            c1[0] = f2bf(k2.x); c1[1] = f2bf(k2.y); c1[2] = f2bf(k2.z); c1[3] = f2bf(k2.w);
            c1[4] = f2bf(k3.x); c1[5] = f2bf(k3.y); c1[6] = f2bf(k3.z); c1[7] = f2bf(k3.w);
            const int swz = (srow & 7) << 4;
            *(s16x8*)(sK + srow * 128 + ((sd0 * 2) ^ swz))      = c0;
            *(s16x8*)(sK + srow * 128 + ((sd0 * 2 + 16) ^ swz)) = c1;

            const float* vsrc = vg + headBase + (size_t)(kc + srow) * HD + sd0;
            float4 v0 = *(const float4*)(vsrc);
            float4 v1 = *(const float4*)(vsrc + 4);
            float4 v2 = *(const float4*)(vsrc + 8);
            float4 v3 = *(const float4*)(vsrc + 12);
            float vv[16] = {v0.x, v0.y, v0.z, v0.w, v1.x, v1.y, v1.z, v1.w,
                            v2.x, v2.y, v2.z, v2.w, v3.x, v3.y, v3.z, v3.w};
#pragma unroll
            for (int e = 0; e < 16; ++e) {
                const int d = sd0 + e;
                *(u16*)(sV + d * 128 + ((srow * 2) ^ (fV(d) << 4))) = f2bf(vv[e]);
            }
        }
        __syncthreads();

        // ---- S = Q K^T, mask, exp, P -> per-wave LDS ----
        char* pw = sP[w];
#pragma unroll
        for (int kt = 0; kt < 4; ++kt) {
            const int krow = kt * 16 + lr;
            const int kswz = (krow & 7) << 4;
            s16x8 kf0 = *(const s16x8*)(sK + krow * 128 + ((lg * 16) ^ kswz));
            s16x8 kf1 = *(const s16x8*)(sK + krow * 128 + ((lg * 16 + 64) ^ kswz));
            f32x4 s = (f32x4){0.f, 0.f, 0.f, 0.f};
            s = __builtin_amdgcn_mfma_f32_16x16x32_bf16(qf[0], kf0, s, 0, 0, 0);
            s = __builtin_amdgcn_mfma_f32_16x16x32_bf16(qf[1], kf1, s, 0, 0, 0);
            const int key = kc + kt * 16 + lr;
#pragma unroll
            for (int r = 0; r < 4; ++r) {
                const int qrow = q0 + w * 16 + lg * 4 + r;
                float pv = 0.f;
                if (key <= qrow && key > qrow - WIN) pv = __expf(s[r] * 0.125f);
                lsum[r] += pv;
                const int prow = lg * 4 + r;
                *(u16*)(pw + prow * 128 + ((kt * 32 + lr * 2) ^ ((prow & 7) << 4))) = f2bf(pv);
            }
        }

        // ---- O += P V (wave-local P; compiler inserts lgkmcnt for RAW) ----
        s16x8 pf0 = *(const s16x8*)(pw + lr * 128 + ((lg * 16) ^ ((lr & 7) << 4)));
        s16x8 pf1 = *(const s16x8*)(pw + lr * 128 + ((lg * 16 + 64) ^ ((lr & 7) << 4)));
#pragma unroll
        for (int td = 0; td < 4; ++td) {
            const int drow = td * 16 + lr;
            const int vswz = fV(drow) << 4;
            s16x8 vf0 = *(const s16x8*)(sV + drow * 128 + ((lg * 16) ^ vswz));
            s16x8 vf1 = *(const s16x8*)(sV + drow * 128 + ((lg * 16 + 64) ^ vswz));
            o[td] = __builtin_amdgcn_mfma_f32_16x16x32_bf16(pf0, vf0, o[td], 0, 0, 0);
            o[td] = __builtin_amdgcn_mfma_f32_16x16x32_bf16(pf1, vf1, o[td], 0, 0, 0);
        }
    }

    // ---- row sums across the 16 key-lanes, normalize, store ----
#pragma unroll
    for (int m = 1; m < 16; m <<= 1) {
#pragma unroll
        for (int r = 0; r < 4; ++r) lsum[r] += __shfl_xor(lsum[r], m, 64);
    }
    float rl[4];
#pragma unroll
    for (int r = 0; r < 4; ++r) rl[r] = 1.f / lsum[r];
#pragma unroll
    for (int td = 0; td < 4; ++td)
#pragma unroll
        for (int r = 0; r < 4; ++r)
            y[(size_t)(q0 + w * 16 + lg * 4 + r) * DIM + h * HD + td * 16 + lr] =
                o[td][r] * rl[r];
}

// ---------------------------------------------------------------------------
// Kernel 2: out = y @ W, fp32 LDS-tiled (near fp32 roofline; MFMA next round).
// ---------------------------------------------------------------------------
__global__ __launch_bounds__(256) void proj_kernel(const float* __restrict__ A,
                                                   const float* __restrict__ W,
                                                   float* __restrict__ out) {
    __shared__ float As[16][68];
    __shared__ float Bs[16][64];

    const int t  = threadIdx.x;
    const int tx = t & 15;
    const int ty = t >> 4;
    const int m0 = blockIdx.y * 64;
    const int n0 = blockIdx.x * 64;

    float acc[4][4];
#pragma unroll
    for (int i = 0; i < 4; ++i)
#pragma unroll
        for (int j = 0; j < 4; ++j) acc[i][j] = 0.f;

    for (int k0 = 0; k0 < DIM; k0 += 16) {
        {
            const int m  = t >> 2;
            const int kk = (t & 3) * 4;
            float4 a = *(const float4*)(A + (size_t)(m0 + m) * DIM + k0 + kk);
            As[kk + 0][m] = a.x;
            As[kk + 1][m] = a.y;
            As[kk + 2][m] = a.z;
            As[kk + 3][m] = a.w;
        }
        {
            const int kk = t >> 4;
            const int n  = (t & 15) * 4;
            *(float4*)&Bs[kk][n] =
                *(const float4*)(W + (size_t)(k0 + kk) * DIM + n0 + n);
        }
        __syncthreads();

#pragma unroll
        for (int kk = 0; kk < 16; ++kk) {
            float4 av = *(const float4*)&As[kk][ty * 4];
            float4 bv = *(const float4*)&Bs[kk][tx * 4];
            acc[0][0] = fmaf(av.x, bv.x, acc[0][0]);
            acc[0][1] = fmaf(av.x, bv.y, acc[0][1]);
            acc[0][2] = fmaf(av.x, bv.z, acc[0][2]);
            acc[0][3] = fmaf(av.x, bv.w, acc[0][3]);
            acc[1][0] = fmaf(av.y, bv.x, acc[1][0]);
            acc[1][1] = fmaf(av.y, bv.y, acc[1][1]);
            acc[1][2] = fmaf(av.y, bv.z, acc[1][2]);
            acc[1][3] = fmaf(av.y, bv.w, acc[1][3]);
            acc[2][0] = fmaf(av.z, bv.x, acc[2][0]);
            acc[2][1] = fmaf(av.z, bv.y, acc[2][1]);
            acc[2][2] = fmaf(av.z, bv.z, acc[2][2]);
            acc[2][3] = fmaf(av.z, bv.w, acc[2][3]);
            acc[3][0] = fmaf(av.w, bv.x, acc[3][0]);
            acc[3][1] = fmaf(av.w, bv.y, acc[3][1]);
            acc[3][2] = fmaf(av.w, bv.z, acc[3][2]);
            acc[3][3] = fmaf(av.w, bv.w, acc[3][3]);
        }
        __syncthreads();
    }

#pragma unroll
    for (int i = 0; i < 4; ++i) {
        float4 o = make_float4(acc[i][0], acc[i][1], acc[i][2], acc[i][3]);
        *(float4*)(out + (size_t)(m0 + ty * 4 + i) * DIM + n0 + tx * 4) = o;
    }
}

extern "C" void kernel_launch(void* const* d_in, const int* in_sizes, int n_in,
                              void* d_out, int out_size, void* d_ws, size_t ws_size,
                              hipStream_t stream) {
    const float* q = (const float*)d_in[0];
    const float* k = (const float*)d_in[1];
    const float* v = (const float*)d_in[2];
    const float* W = (const float*)d_in[3];
    float* out = (float*)d_out;
    float* y   = (float*)d_ws;  // (T, DIM) fp32 intermediate = 8 MB

    dim3 gA(T_SEQ / 64, NH);
    attn_kernel<<<gA, 256, 0, stream>>>(q, k, v, y);

    dim3 gP(DIM / 64, T_SEQ / 64);
    proj_kernel<<<gP, 256, 0, stream>>>(y, W, out);
}

// Round 3
// 45.547 us; speedup vs baseline: 6.3360x; 1.9186x over previous
//
#include <hip/hip_runtime.h>
#include <math.h>

#define T_SEQ 2048
#define NH    16
#define HD    64
#define DIM   1024
#define WIN   256

typedef __attribute__((ext_vector_type(4))) float f32x4;
typedef __attribute__((ext_vector_type(8))) short s16x8;
typedef unsigned short u16;

static __device__ __forceinline__ u16 f2bf(float f) {
    unsigned u = __builtin_bit_cast(unsigned, f);
    u += 0x7fff + ((u >> 16) & 1);   // RNE; inputs finite
    return (u16)(u >> 16);
}

static __device__ __forceinline__ int fV(int d) { return (d & 7) ^ ((d >> 3) & 7); }

static __device__ __forceinline__ void gload16(const void* g, void* l) {
    __builtin_amdgcn_global_load_lds(
        (const __attribute__((address_space(1))) unsigned int*)g,
        (__attribute__((address_space(3))) unsigned int*)l, 16, 0, 0);
}

// ---------------------------------------------------------------------------
// W (K x N fp32) -> Wt (N x K bf16), LDS tile transpose. grid (K/64, N/64).
// ---------------------------------------------------------------------------
__global__ __launch_bounds__(256) void wconv_kernel(const float* __restrict__ W,
                                                    u16* __restrict__ Wt) {
    __shared__ float sT[64][68];
    const int t  = threadIdx.x;
    const int k0 = blockIdx.x * 64;
    const int n0 = blockIdx.y * 64;
#pragma unroll
    for (int i = 0; i < 4; ++i) {
        const int idx = i * 256 + t;
        const int kr = idx >> 4, c4 = (idx & 15) * 4;
        float4 v = *(const float4*)(W + (size_t)(k0 + kr) * DIM + n0 + c4);
        sT[kr][c4] = v.x; sT[kr][c4 + 1] = v.y; sT[kr][c4 + 2] = v.z; sT[kr][c4 + 3] = v.w;
    }
    __syncthreads();
#pragma unroll
    for (int i = 0; i < 2; ++i) {
        const int idx = i * 256 + t;
        const int nr = idx >> 3, ch = (idx & 7) * 8;
        s16x8 o;
#pragma unroll
        for (int e = 0; e < 8; ++e) o[e] = f2bf(sT[ch + e][nr]);
        *(s16x8*)(Wt + (size_t)(n0 + nr) * DIM + k0 + ch) = o;
    }
}

// ---------------------------------------------------------------------------
// Sliding-window attention, bf16 MFMA flash-style (round-2 kernel, bf16 out).
// grid=(T/64, H), block=256 (4 waves).
// ---------------------------------------------------------------------------
__global__ __launch_bounds__(256) void attn_kernel(const float* __restrict__ qg,
                                                   const float* __restrict__ kg,
                                                   const float* __restrict__ vg,
                                                   u16* __restrict__ y) {
    __shared__ __align__(16) char sK[64 * 128];     // bf16 [key][d], swz (key&7)<<4
    __shared__ __align__(16) char sV[64 * 128];     // bf16 [d][key], swz fV(d)<<4
    __shared__ __align__(16) char sP[4][16 * 128];  // per-wave bf16 [q][key]

    const int t    = threadIdx.x;
    const int lane = t & 63;
    const int w    = t >> 6;
    const int q0   = blockIdx.x * 64;
    const int h    = blockIdx.y;
    const size_t headBase = (size_t)h * T_SEQ * HD;

    const int lr = lane & 15;
    const int lg = lane >> 4;

    s16x8 qf[2];
    {
        const float* qrow = qg + headBase + (size_t)(q0 + w * 16 + lr) * HD + lg * 8;
#pragma unroll
        for (int s = 0; s < 2; ++s) {
            float4 a = *(const float4*)(qrow + 32 * s);
            float4 b = *(const float4*)(qrow + 32 * s + 4);
            s16x8 f;
            f[0] = f2bf(a.x); f[1] = f2bf(a.y); f[2] = f2bf(a.z); f[3] = f2bf(a.w);
            f[4] = f2bf(b.x); f[5] = f2bf(b.y); f[6] = f2bf(b.z); f[7] = f2bf(b.w);
            qf[s] = f;
        }
    }

    f32x4 o[4];
#pragma unroll
    for (int i = 0; i < 4; ++i) o[i] = (f32x4){0.f, 0.f, 0.f, 0.f};
    float lsum[4] = {0.f, 0.f, 0.f, 0.f};

    int lo = q0 - (WIN - 1);
    if (lo < 0) lo = 0;
    const int kc0 = lo & ~63;

    const int srow = t >> 2;
    const int sd0  = (t & 3) * 16;

    for (int kc = kc0; kc <= q0; kc += 64) {
        __syncthreads();
        {
            const float* ksrc = kg + headBase + (size_t)(kc + srow) * HD + sd0;
            float4 k0 = *(const float4*)(ksrc);
            float4 k1 = *(const float4*)(ksrc + 4);
            float4 k2 = *(const float4*)(ksrc + 8);
            float4 k3 = *(const float4*)(ksrc + 12);
            s16x8 c0, c1;
            c0[0] = f2bf(k0.x); c0[1] = f2bf(k0.y); c0[2] = f2bf(k0.z); c0[3] = f2bf(k0.w);
            c0[4] = f2bf(k1.x); c0[5] = f2bf(k1.y); c0[6] = f2bf(k1.z); c0[7] = f2bf(k1.w);
            c1[0] = f2bf(k2.x); c1[1] = f2bf(k2.y); c1[2] = f2bf(k2.z); c1[3] = f2bf(k2.w);
            c1[4] = f2bf(k3.x); c1[5] = f2bf(k3.y); c1[6] = f2bf(k3.z); c1[7] = f2bf(k3.w);
            const int swz = (srow & 7) << 4;
            *(s16x8*)(sK + srow * 128 + ((sd0 * 2) ^ swz))      = c0;
            *(s16x8*)(sK + srow * 128 + ((sd0 * 2 + 16) ^ swz)) = c1;

            const float* vsrc = vg + headBase + (size_t)(kc + srow) * HD + sd0;
            float4 v0 = *(const float4*)(vsrc);
            float4 v1 = *(const float4*)(vsrc + 4);
            float4 v2 = *(const float4*)(vsrc + 8);
            float4 v3 = *(const float4*)(vsrc + 12);
            float vv[16] = {v0.x, v0.y, v0.z, v0.w, v1.x, v1.y, v1.z, v1.w,
                            v2.x, v2.y, v2.z, v2.w, v3.x, v3.y, v3.z, v3.w};
#pragma unroll
            for (int e = 0; e < 16; ++e) {
                const int d = sd0 + e;
                *(u16*)(sV + d * 128 + ((srow * 2) ^ (fV(d) << 4))) = f2bf(vv[e]);
            }
        }
        __syncthreads();

        char* pw = sP[w];
#pragma unroll
        for (int kt = 0; kt < 4; ++kt) {
            const int krow = kt * 16 + lr;
            const int kswz = (krow & 7) << 4;
            s16x8 kf0 = *(const s16x8*)(sK + krow * 128 + ((lg * 16) ^ kswz));
            s16x8 kf1 = *(const s16x8*)(sK + krow * 128 + ((lg * 16 + 64) ^ kswz));
            f32x4 s = (f32x4){0.f, 0.f, 0.f, 0.f};
            s = __builtin_amdgcn_mfma_f32_16x16x32_bf16(qf[0], kf0, s, 0, 0, 0);
            s = __builtin_amdgcn_mfma_f32_16x16x32_bf16(qf[1], kf1, s, 0, 0, 0);
            const int key = kc + kt * 16 + lr;
#pragma unroll
            for (int r = 0; r < 4; ++r) {
                const int qrow = q0 + w * 16 + lg * 4 + r;
                float pv = 0.f;
                if (key <= qrow && key > qrow - WIN) pv = __expf(s[r] * 0.125f);
                lsum[r] += pv;
                const int prow = lg * 4 + r;
                *(u16*)(pw + prow * 128 + ((kt * 32 + lr * 2) ^ ((prow & 7) << 4))) = f2bf(pv);
            }
        }

        s16x8 pf0 = *(const s16x8*)(pw + lr * 128 + ((lg * 16) ^ ((lr & 7) << 4)));
        s16x8 pf1 = *(const s16x8*)(pw + lr * 128 + ((lg * 16 + 64) ^ ((lr & 7) << 4)));
#pragma unroll
        for (int td = 0; td < 4; ++td) {
            const int drow = td * 16 + lr;
            const int vswz = fV(drow) << 4;
            s16x8 vf0 = *(const s16x8*)(sV + drow * 128 + ((lg * 16) ^ vswz));
            s16x8 vf1 = *(const s16x8*)(sV + drow * 128 + ((lg * 16 + 64) ^ vswz));
            o[td] = __builtin_amdgcn_mfma_f32_16x16x32_bf16(pf0, vf0, o[td], 0, 0, 0);
            o[td] = __builtin_amdgcn_mfma_f32_16x16x32_bf16(pf1, vf1, o[td], 0, 0, 0);
        }
    }

#pragma unroll
    for (int m = 1; m < 16; m <<= 1) {
#pragma unroll
        for (int r = 0; r < 4; ++r) lsum[r] += __shfl_xor(lsum[r], m, 64);
    }
    float rl[4];
#pragma unroll
    for (int r = 0; r < 4; ++r) rl[r] = 1.f / lsum[r];
#pragma unroll
    for (int td = 0; td < 4; ++td)
#pragma unroll
        for (int r = 0; r < 4; ++r)
            y[(size_t)(q0 + w * 16 + lg * 4 + r) * DIM + h * HD + td * 16 + lr] =
                f2bf(o[td][r] * rl[r]);
}

// ---------------------------------------------------------------------------
// proj: out = y @ W via bf16 MFMA. A = y (M x K bf16), Bt = Wt (N x K bf16).
// BM=128 BN=64 BK=64, 256 thr / 4 waves (2x2), wave tile 64x32.
// global_load_lds (linear dest, inverse-swizzled source) + XOR-swz ds_read.
// grid (N/64, M/128) = (16,16) = 256 blocks.
// ---------------------------------------------------------------------------
__global__ __launch_bounds__(256) void proj_kernel(const u16* __restrict__ A,
                                                   const u16* __restrict__ Bt,
                                                   float* __restrict__ out) {
    __shared__ __align__(16) char sA[2][128 * 128];  // [m][k] bf16, 16KB each
    __shared__ __align__(16) char sB[2][64 * 128];   // [n][k] bf16, 8KB each

    const int t    = threadIdx.x;
    const int lane = t & 63;
    const int w    = t >> 6;
    const int wr   = w >> 1, wc = w & 1;
    const int lr   = lane & 15, lg = lane >> 4;
    const int m0   = (int)blockIdx.y * 128;
    const int n0   = (int)blockIdx.x * 64;

    f32x4 acc[4][2];
#pragma unroll
    for (int i = 0; i < 4; ++i)
#pragma unroll
        for (int j = 0; j < 2; ++j) acc[i][j] = (f32x4){0.f, 0.f, 0.f, 0.f};

    // staging lane geometry: within each 1KB wave-pass, lane l covers
    // linear bytes base + l*16; row = lin/128, chunk = (lin/16)&7.
    const int aRowBase = w * 8 + (lane >> 3);  // + pass*32
    const int aChunk   = lane & 7;

#define STAGE(buf, k0)                                                               \
    do {                                                                             \
        _Pragma("unroll") for (int p = 0; p < 4; ++p) {                              \
            const int row = p * 32 + aRowBase;                                       \
            gload16(A + (size_t)(m0 + row) * DIM + (k0) + ((aChunk ^ (row & 7)) << 3),\
                    sA[buf] + p * 4096 + w * 1024);                                  \
        }                                                                            \
        _Pragma("unroll") for (int p = 0; p < 2; ++p) {                              \
            const int row = p * 32 + aRowBase;                                       \
            gload16(Bt + (size_t)(n0 + row) * DIM + (k0) + ((aChunk ^ (row & 7)) << 3),\
                    sB[buf] + p * 4096 + w * 1024);                                  \
        }                                                                            \
    } while (0)

    STAGE(0, 0);
    __syncthreads();

    for (int kt = 0; kt < DIM / 64; ++kt) {
        const int buf = kt & 1;
        if (kt < DIM / 64 - 1) STAGE(buf ^ 1, (kt + 1) * 64);

        s16x8 af[2][4], bfr[2][2];
#pragma unroll
        for (int kh = 0; kh < 2; ++kh) {
#pragma unroll
            for (int mi = 0; mi < 4; ++mi) {
                const int row = wr * 64 + mi * 16 + lr;
                const int cc  = kh * 4 + lg;
                af[kh][mi] = *(const s16x8*)(sA[buf] + row * 128 + ((cc ^ (row & 7)) << 4));
            }
#pragma unroll
            for (int ni = 0; ni < 2; ++ni) {
                const int row = wc * 32 + ni * 16 + lr;
                const int cc  = kh * 4 + lg;
                bfr[kh][ni] = *(const s16x8*)(sB[buf] + row * 128 + ((cc ^ (row & 7)) << 4));
            }
        }
#pragma unroll
        for (int kh = 0; kh < 2; ++kh)
#pragma unroll
            for (int mi = 0; mi < 4; ++mi)
#pragma unroll
                for (int ni = 0; ni < 2; ++ni)
                    acc[mi][ni] = __builtin_amdgcn_mfma_f32_16x16x32_bf16(
                        af[kh][mi], bfr[kh][ni], acc[mi][ni], 0, 0, 0);
        __syncthreads();
    }
#undef STAGE

#pragma unroll
    for (int mi = 0; mi < 4; ++mi)
#pragma unroll
        for (int ni = 0; ni < 2; ++ni)
#pragma unroll
            for (int r = 0; r < 4; ++r)
                out[(size_t)(m0 + wr * 64 + mi * 16 + lg * 4 + r) * DIM +
                    n0 + wc * 32 + ni * 16 + lr] = acc[mi][ni][r];
}

extern "C" void kernel_launch(void* const* d_in, const int* in_sizes, int n_in,
                              void* d_out, int out_size, void* d_ws, size_t ws_size,
                              hipStream_t stream) {
    const float* q = (const float*)d_in[0];
    const float* k = (const float*)d_in[1];
    const float* v = (const float*)d_in[2];
    const float* W = (const float*)d_in[3];
    float* out = (float*)d_out;
    u16* y_bf = (u16*)d_ws;                       // (T, DIM) bf16 = 4MB
    u16* Wt   = (u16*)d_ws + (size_t)T_SEQ * DIM; // (DIM, DIM) bf16 = 2MB

    dim3 gW(DIM / 64, DIM / 64);
    wconv_kernel<<<gW, 256, 0, stream>>>(W, Wt);

    dim3 gA(T_SEQ / 64, NH);
    attn_kernel<<<gA, 256, 0, stream>>>(q, k, v, y_bf);

    dim3 gP(DIM / 64, T_SEQ / 128);
    proj_kernel<<<gP, 256, 0, stream>>>(y_bf, Wt, out);
}